// Round 8
// baseline (173.802 us; speedup 1.0000x reference)
//
#include <hip/hip_runtime.h>
#include <cstdint>
#include <cstddef>

typedef __bf16 bf16_t;
typedef bf16_t bf16x8 __attribute__((ext_vector_type(8)));
typedef float f32x4 __attribute__((ext_vector_type(4)));

__device__ inline bf16x8 load8(const float* p) {
  f32x4 a = *reinterpret_cast<const f32x4*>(p);
  f32x4 b = *reinterpret_cast<const f32x4*>(p + 4);
  bf16x8 r;
  r[0] = (bf16_t)a[0]; r[1] = (bf16_t)a[1];
  r[2] = (bf16_t)a[2]; r[3] = (bf16_t)a[3];
  r[4] = (bf16_t)b[0]; r[5] = (bf16_t)b[1];
  r[6] = (bf16_t)b[2]; r[7] = (bf16_t)b[3];
  return r;
}
__device__ inline bf16x8 load8(const bf16_t* p) {
  return *reinterpret_cast<const bf16x8*>(p);
}

// Async global->LDS 16B copy (gfx950). LDS dst is wave-uniform base +
// lane*16; global src is per-lane.
__device__ inline void gload_lds16(const bf16_t* g, bf16_t* l) {
  __builtin_amdgcn_global_load_lds(
      (const __attribute__((address_space(1))) void*)g,
      (__attribute__((address_space(3))) void*)l, 16, 0, 0);
}

// ---------------------------------------------------------------------------
// Fused convert: blocks 0..2047 copy x fp32->bf16; blocks 2048..2687 build
// the bf16-transposed weights (64x64 LDS tiles).
// ---------------------------------------------------------------------------
__global__ __launch_bounds__(256) void cvt_all_k(
    const float* __restrict__ x, bf16_t* __restrict__ xb,
    const float* __restrict__ Wq, const float* __restrict__ Wk,
    const float* __restrict__ Wv, const float* __restrict__ Wo,
    bf16_t* __restrict__ wqT, bf16_t* __restrict__ wkT,
    bf16_t* __restrict__ wvT, bf16_t* __restrict__ woT) {
  __shared__ bf16_t Ts[64][72];
  const int tid = threadIdx.x;
  if (blockIdx.x < 2048) {
    const size_t i = (size_t)blockIdx.x * 2048 + (size_t)tid * 8;
    *reinterpret_cast<bf16x8*>(xb + i) = load8(x + i);
    return;
  }
  const int b = blockIdx.x - 2048;
  const float* S;
  bf16_t* D;
  int N, idx;
  if (b < 256) { S = Wq; D = wqT; N = 1024; idx = b; }
  else if (b < 320) { S = Wk; D = wkT; N = 256; idx = b - 256; }
  else if (b < 384) { S = Wv; D = wvT; N = 256; idx = b - 320; }
  else { S = Wo; D = woT; N = 1024; idx = b - 384; }
  const int ntl = (N == 1024) ? 4 : 2;  // log2(n-tiles)
  const int kt0 = (idx >> ntl) * 64;
  const int n0 = (idx & ((1 << ntl) - 1)) * 64;
#pragma unroll
  for (int i = 0; i < 2; ++i) {
    const int c = tid + 256 * i;
    const int row = c >> 3, col0 = (c & 7) * 8;
    *reinterpret_cast<bf16x8*>(&Ts[row][col0]) =
        load8(&S[(size_t)(kt0 + row) * N + n0 + col0]);
  }
  __syncthreads();
#pragma unroll
  for (int i = 0; i < 2; ++i) {
    const int c = tid + 256 * i;
    const int nrow = c >> 3, k0 = (c & 7) * 8;
    bf16x8 v;
#pragma unroll
    for (int j = 0; j < 8; ++j) v[j] = Ts[k0 + j][nrow];
    *reinterpret_cast<bf16x8*>(&D[(size_t)(n0 + nrow) * 1024 + kt0 + k0]) = v;
  }
}

// ---------------------------------------------------------------------------
// 128x64 GEMM body, B^T form: C = A[M,K] * BT[N,K]^T, all bf16, BK=32.
// gload_lds staging, LDS double-buffered, one barrier per K-step.
// Linear LDS with k-block XOR swizzle cb ^= (row>>1)&3 applied inversely on
// the per-lane GLOBAL src (rule 21). qkv grid 768 = 3.0 blocks/CU,
// out-proj 512 = 2.0/CU.
// MFMA layouts (verified m89):
//   A: lane holds A[m=lane&15][k=(lane>>4)*8+j]
//   B: lane holds B[k=(lane>>4)*8+j][n=lane&15]  (= BT[n][k] rows)
//   C/D: row=(lane>>4)*4+reg, col=lane&15
// ---------------------------------------------------------------------------
__device__ inline void stage_gldsA(const bf16_t* __restrict__ G, int grow0,
                                   int gK, int k0, bf16_t* lds, int w, int l) {
#pragma unroll
  for (int i = 0; i < 2; ++i) {
    const int seg = w * 2 + i;                // 0..7
    const int r = (seg << 4) + (l >> 2);      // tile row 0..127
    const int cb = (l & 3) ^ ((r >> 1) & 3);  // swizzled global k-block
    gload_lds16(G + (size_t)(grow0 + r) * gK + k0 + cb * 8, lds + (seg << 9));
  }
}
__device__ inline void stage_gldsB(const bf16_t* __restrict__ G, int grow0,
                                   int gK, int k0, bf16_t* lds, int w, int l) {
  const int r = (w << 4) + (l >> 2);        // tile row 0..63
  const int cb = (l & 3) ^ ((r >> 1) & 3);  // swizzled global k-block
  gload_lds16(G + (size_t)(grow0 + r) * gK + k0 + cb * 8, lds + (w << 9));
}

template <typename OutT>
__device__ inline void gemm_bt_body(const bf16_t* __restrict__ A,
                                    const bf16_t* __restrict__ BT,
                                    OutT* __restrict__ C, int m0, int bt0,
                                    int K, int CN, int cn0, float alpha) {
  __shared__ __align__(16) bf16_t As[2][128][32];
  __shared__ __align__(16) bf16_t Bs[2][64][32];  // [n][k]

  const int tid = threadIdx.x;
  const int wave = tid >> 6, lane = tid & 63;
  const int quad = lane >> 4, l16 = lane & 15;
  const int moff = (wave & 1) * 64, noff = (wave >> 1) * 32;

  f32x4 acc[4][2];
#pragma unroll
  for (int mt = 0; mt < 4; ++mt)
#pragma unroll
    for (int nt = 0; nt < 2; ++nt) acc[mt][nt] = {0.f, 0.f, 0.f, 0.f};

  stage_gldsA(A, m0, K, 0, &As[0][0][0], wave, lane);
  stage_gldsB(BT, bt0, K, 0, &Bs[0][0][0], wave, lane);

  for (int k0 = 0; k0 < K; k0 += 32) {
    const int c = (k0 >> 5) & 1;
    __syncthreads();  // vmcnt(0) drain: buffer c ready; buffer c^1 free
    if (k0 + 32 < K) {
      stage_gldsA(A, m0, K, k0 + 32, &As[c ^ 1][0][0], wave, lane);
      stage_gldsB(BT, bt0, K, k0 + 32, &Bs[c ^ 1][0][0], wave, lane);
    }
    bf16x8 af[4], bfr[2];
#pragma unroll
    for (int mt = 0; mt < 4; ++mt) {
      const int row = moff + mt * 16 + l16;
      af[mt] = *reinterpret_cast<const bf16x8*>(
          &As[c][row][(quad ^ ((row >> 1) & 3)) * 8]);
    }
#pragma unroll
    for (int nt = 0; nt < 2; ++nt) {
      const int row = noff + nt * 16 + l16;
      bfr[nt] = *reinterpret_cast<const bf16x8*>(
          &Bs[c][row][(quad ^ ((row >> 1) & 3)) * 8]);
    }
#pragma unroll
    for (int mt = 0; mt < 4; ++mt)
#pragma unroll
      for (int nt = 0; nt < 2; ++nt)
        acc[mt][nt] = __builtin_amdgcn_mfma_f32_16x16x32_bf16(
            af[mt], bfr[nt], acc[mt][nt], 0, 0, 0);
  }

#pragma unroll
  for (int mt = 0; mt < 4; ++mt) {
    const int crow = m0 + moff + mt * 16 + quad * 4;
#pragma unroll
    for (int nt = 0; nt < 2; ++nt) {
      const int ccol = cn0 + noff + nt * 16 + l16;
#pragma unroll
      for (int r = 0; r < 4; ++r)
        C[(size_t)(crow + r) * CN + ccol] = (OutT)(acc[mt][nt][r] * alpha);
    }
  }
}

// Fused QKV projection: 64-wide n-tiles [Wq 0..15 | Wk 16..19 | Wv 20..23].
__global__ __launch_bounds__(256, 3) void qkv_k(
    const bf16_t* __restrict__ x, const bf16_t* __restrict__ wqT,
    const bf16_t* __restrict__ wkT, const bf16_t* __restrict__ wvT,
    bf16_t* __restrict__ Qo, bf16_t* __restrict__ Ko, bf16_t* __restrict__ Vo) {
  const int n0 = blockIdx.x * 64;
  const int m0 = blockIdx.y * 128;
  const bf16_t* BT;
  bf16_t* C;
  int CN, bn0;
  float alpha;
  if (n0 < 1024) {
    BT = wqT; C = Qo; CN = 1024; bn0 = n0; alpha = 0.125f;  // attn scale
  } else if (n0 < 1280) {
    BT = wkT; C = Ko; CN = 256; bn0 = n0 - 1024; alpha = 1.0f;
  } else {
    BT = wvT; C = Vo; CN = 256; bn0 = n0 - 1280; alpha = 1.0f;
  }
  gemm_bt_body<bf16_t>(x, BT, C, m0, bn0, 1024, CN, bn0, alpha);
}

// Plain B^T GEMM (attn @ Wo^T^T), 64-wide n-tiles.
template <typename OutT>
__global__ __launch_bounds__(256, 3) void gemm_bt_k(
    const bf16_t* __restrict__ A, const bf16_t* __restrict__ BT,
    OutT* __restrict__ C, int K, int N, float alpha) {
  gemm_bt_body<OutT>(A, BT, C, blockIdx.y * 128, blockIdx.x * 64, K, N,
                     blockIdx.x * 64, alpha);
}

// ---------------------------------------------------------------------------
// Transpose V [4096,256] -> VT[(g*4+kh)*64 + d][key].
// ---------------------------------------------------------------------------
__global__ __launch_bounds__(256) void transpose_v_k(
    const bf16_t* __restrict__ V, bf16_t* __restrict__ VT) {
  __shared__ bf16_t Vs[64][72];
  const int tid = threadIdx.x;
  const int kt0 = blockIdx.x * 64;
  const int ghk = blockIdx.y;  // g*4+kh
  const int g = ghk >> 2, kh = ghk & 3;
#pragma unroll
  for (int i = 0; i < 2; ++i) {
    const int c = tid + 256 * i;
    const int row = c >> 3, d0 = (c & 7) * 8;
    *reinterpret_cast<bf16x8*>(&Vs[row][d0]) = *reinterpret_cast<const bf16x8*>(
        &V[((size_t)(kt0 + row) * 2 + g) * 256 + kh * 64 + d0]);
  }
  __syncthreads();
#pragma unroll
  for (int i = 0; i < 2; ++i) {
    const int c = tid + 256 * i;
    const int d = c >> 3, k0 = (c & 7) * 8;
    bf16x8 v;
#pragma unroll
    for (int j = 0; j < 8; ++j) v[j] = Vs[k0 + j][d];
    *reinterpret_cast<bf16x8*>(&VT[((size_t)ghk * 64 + d) * 2048 + kt0 + k0]) =
        v;
  }
}

// ---------------------------------------------------------------------------
// Flash attention v12 = flash9's 2-wave x 32-q-row compute body (half the
// K/V LDS-read redundancy of the 4x16 split: each wave re-reads the full
// 16 KB K/V tile, so 2 waves = 32 KB/iter vs 64 KB) + flash11's verified
// K/V double-buffer one-barrier pipeline (hides the latency that made the
// 2-barrier 2-wave flash9 stall at 61 µs).
// LDS model (m134 cyc): 2x16 b128 reads 384 + Ps 64 b16 384 + pf 96 +
// stage 96 = 960 cyc/iter vs flash10/11's 1344 -> predicted ~28-32 µs.
// LDS 40 KB (Ks[2] 16K + Vs[2] 16K + Ps[2][32][64] 8K) -> 4 blocks/CU
// = 160 KiB, 8 waves/CU. __launch_bounds__(128,2): flash9-verified tier
// (VGPR cap 256, no spill risk - r2/r5 lessons).
// ---------------------------------------------------------------------------
__global__ __launch_bounds__(128, 2) void flash12_k(
    const bf16_t* __restrict__ Q, const bf16_t* __restrict__ K,
    const bf16_t* __restrict__ VT, bf16_t* __restrict__ ATTN) {
  __shared__ __align__(16) bf16_t Ks[2][64][64];
  __shared__ __align__(16) bf16_t Vs[2][64][64];  // [d][key_local], swizzled
  __shared__ __align__(16) bf16_t Ps[2][32][64];

  const int tid = threadIdx.x;
  const int w = tid >> 6, lane = tid & 63;
  const int quad = lane >> 4, l16 = lane & 15;
  const int b = blockIdx.x;
  const int gh = blockIdx.y;
  const int j8 = b & 7;
  const int i8e = ((b >> 3) + (gh >> 3)) & 3;  // gh-rotated length class
  const int T = (i8e == 0) ? j8
              : (i8e == 1) ? (15 - j8)
              : (i8e == 2) ? (16 + j8)
                           : (31 - j8);
  const int g = gh >> 4, h = gh & 15, kh = h >> 2;
  const int qbase = T * 64 + w * 32;
  const int swz = ((l16 >> 2) & 3) << 4;
  const int rsw = l16 & 7;  // row-dependent K/V col-block swizzle key

  bf16x8 qf[2][2];
#pragma unroll
  for (int rg = 0; rg < 2; ++rg)
#pragma unroll
    for (int t = 0; t < 2; ++t)
      qf[rg][t] = *reinterpret_cast<const bf16x8*>(
          &Q[((size_t)(qbase + rg * 16 + l16) * 2 + g) * 1024 + h * 64 +
             t * 32 + quad * 8]);

  f32x4 O[2][4];
  f32x4 lp[2];
#pragma unroll
  for (int rg = 0; rg < 2; ++rg) {
    lp[rg] = {0.f, 0.f, 0.f, 0.f};
#pragma unroll
    for (int d = 0; d < 4; ++d) O[rg][d] = {0.f, 0.f, 0.f, 0.f};
  }

  bf16x8 kr[4], vr[4];
  // Relay load for key-tile starting at key nt0 (128-thread layout).
  auto load_tile = [&](int nt0) {
#pragma unroll
    for (int i = 0; i < 4; ++i) {
      const int c = tid + 128 * i;
      const int row = c >> 3, e0 = (c & 7) * 8;
      kr[i] = *reinterpret_cast<const bf16x8*>(
          &K[((size_t)(nt0 + row) * 2 + g) * 256 + kh * 64 + e0]);
      vr[i] = *reinterpret_cast<const bf16x8*>(
          &VT[((size_t)(g * 4 + kh) * 64 + row) * 2048 + nt0 + e0]);
    }
  };
  auto stage_tile = [&](int buf) {
#pragma unroll
    for (int i = 0; i < 4; ++i) {
      const int c = tid + 128 * i;
      const int row = c >> 3;
      const int pb = (((c & 7) ^ (row & 7)) << 3);  // swizzled col block
      *reinterpret_cast<bf16x8*>(&Ks[buf][row][pb]) = kr[i];
      *reinterpret_cast<bf16x8*>(&Vs[buf][row][pb]) = vr[i];
    }
  };

  load_tile(0);
  stage_tile(0);
  if (T > 0) load_tile(64);
  __syncthreads();

  int cbuf = 0;
  for (int kt = 0; kt <= T; ++kt) {
    if (kt < T) stage_tile(cbuf ^ 1);           // data for tile kt+1
    if (kt + 2 <= T) load_tile((kt + 2) * 64);  // relay for tile kt+2

    f32x4 s[2][4];
    __builtin_amdgcn_s_setprio(1);
#pragma unroll
    for (int nt = 0; nt < 4; ++nt) {
      bf16x8 kf0 = *reinterpret_cast<const bf16x8*>(
          &Ks[cbuf][nt * 16 + l16][(quad ^ rsw) << 3]);
      bf16x8 kf1 = *reinterpret_cast<const bf16x8*>(
          &Ks[cbuf][nt * 16 + l16][((4 + quad) ^ rsw) << 3]);
#pragma unroll
      for (int rg = 0; rg < 2; ++rg) {
        f32x4 z = {0.f, 0.f, 0.f, 0.f};
        z = __builtin_amdgcn_mfma_f32_16x16x32_bf16(qf[rg][0], kf0, z, 0, 0, 0);
        s[rg][nt] =
            __builtin_amdgcn_mfma_f32_16x16x32_bf16(qf[rg][1], kf1, z, 0, 0, 0);
      }
    }
    __builtin_amdgcn_s_setprio(0);
    const bool diag = (kt == T);
#pragma unroll
    for (int rg = 0; rg < 2; ++rg) {
#pragma unroll
      for (int nt = 0; nt < 4; ++nt) {
        const int key = nt * 16 + l16;
#pragma unroll
        for (int r = 0; r < 4; ++r) {
          float p = __expf(s[rg][nt][r]);
          if (diag && key > w * 32 + rg * 16 + quad * 4 + r) p = 0.f;
          lp[rg][r] += p;
          Ps[w][rg * 16 + quad * 4 + r][((nt ^ quad) << 4) + l16] = (bf16_t)p;
        }
      }
    }
    bf16x8 pf[2][2];
#pragma unroll
    for (int rg = 0; rg < 2; ++rg)
#pragma unroll
      for (int t = 0; t < 2; ++t)
        pf[rg][t] = *reinterpret_cast<const bf16x8*>(
            &Ps[w][rg * 16 + l16][(t * 32 + quad * 8) ^ swz]);
    __builtin_amdgcn_s_setprio(1);
#pragma unroll
    for (int dnt = 0; dnt < 4; ++dnt) {
      bf16x8 vf0 = *reinterpret_cast<const bf16x8*>(
          &Vs[cbuf][dnt * 16 + l16][(quad ^ rsw) << 3]);
      bf16x8 vf1 = *reinterpret_cast<const bf16x8*>(
          &Vs[cbuf][dnt * 16 + l16][((4 + quad) ^ rsw) << 3]);
#pragma unroll
      for (int rg = 0; rg < 2; ++rg) {
        O[rg][dnt] = __builtin_amdgcn_mfma_f32_16x16x32_bf16(
            pf[rg][0], vf0, O[rg][dnt], 0, 0, 0);
        O[rg][dnt] = __builtin_amdgcn_mfma_f32_16x16x32_bf16(
            pf[rg][1], vf1, O[rg][dnt], 0, 0, 0);
      }
    }
    __builtin_amdgcn_s_setprio(0);
    __syncthreads();
    cbuf ^= 1;
  }

#pragma unroll
  for (int rg = 0; rg < 2; ++rg) {
#pragma unroll
    for (int off = 1; off < 16; off <<= 1)
#pragma unroll
      for (int r = 0; r < 4; ++r) lp[rg][r] += __shfl_xor(lp[rg][r], off, 64);
#pragma unroll
    for (int r = 0; r < 4; ++r) {
      const float inv = 1.f / lp[rg][r];
      const int row = qbase + rg * 16 + quad * 4 + r;
#pragma unroll
      for (int dnt = 0; dnt < 4; ++dnt)
        ATTN[((size_t)row * 2 + g) * 1024 + h * 64 + dnt * 16 + l16] =
            (bf16_t)(O[rg][dnt][r] * inv);
    }
  }
}

// ---------------------------------------------------------------------------
extern "C" void kernel_launch(void* const* d_in, const int* in_sizes, int n_in,
                              void* d_out, int out_size, void* d_ws,
                              size_t ws_size, hipStream_t stream) {
  (void)in_sizes;
  (void)n_in;
  (void)out_size;
  (void)ws_size;

  const float* x = (const float*)d_in[0];   // [4096,1024] fp32
  const float* Wq = (const float*)d_in[1];  // [1024,1024]
  const float* Wk = (const float*)d_in[2];  // [1024,256]
  const float* Wv = (const float*)d_in[3];  // [1024,256]
  const float* Wo = (const float*)d_in[4];  // [1024,1024]
  float* out = (float*)d_out;               // [4096,1024] fp32 (16 MB)

  const size_t MB = 1024 * 1024;
  // d_out: [0,8M) Qtmp | [8M,10M) VT | [10M,13M) wqT/wkT/wvT | [13M,15M) Vo
  // (all dead before the final GEMM writes out; final GEMM reads only ws).
  char* ob = (char*)d_out;
  bf16_t* Qtmp = (bf16_t*)ob;
  bf16_t* VTws = (bf16_t*)(ob + 8 * MB);
  bf16_t* wqT = (bf16_t*)(ob + 10 * MB);
  bf16_t* wkT = (bf16_t*)(ob + 12 * MB);
  bf16_t* wvT = (bf16_t*)(ob + 12 * MB + 512 * 1024);
  bf16_t* Vws = (bf16_t*)(ob + 13 * MB);
  // ws (12 MB): [0,2M) K | [2M,4M) woT | [4M,12M) ATTN (xb borrows upfront).
  char* wb = (char*)d_ws;
  bf16_t* Kws = (bf16_t*)wb;
  bf16_t* woT = (bf16_t*)(wb + 2 * MB);
  bf16_t* ATTNws = (bf16_t*)(wb + 4 * MB);
  bf16_t* xb = ATTNws;  // 8 MB, dead once flash starts writing ATTN

  cvt_all_k<<<dim3(2688), dim3(256), 0, stream>>>(x, xb, Wq, Wk, Wv, Wo, wqT,
                                                  wkT, wvT, woT);
  qkv_k<<<dim3(24, 32), dim3(256), 0, stream>>>(xb, wqT, wkT, wvT, Qtmp, Kws,
                                                Vws);
  transpose_v_k<<<dim3(32, 8), dim3(256), 0, stream>>>(Vws, VTws);
  flash12_k<<<dim3(32, 32), dim3(128), 0, stream>>>(Qtmp, Kws, VTws, ATTNws);
  gemm_bt_k<float><<<dim3(16, 32), dim3(256), 0, stream>>>(ATTNws, woT, out,
                                                           1024, 1024, 1.0f);
}

// Round 10
// 164.228 us; speedup vs baseline: 1.0583x; 1.0583x over previous
//
#include <hip/hip_runtime.h>
#include <cstdint>
#include <cstddef>

typedef __bf16 bf16_t;
typedef bf16_t bf16x4 __attribute__((ext_vector_type(4)));
typedef bf16_t bf16x8 __attribute__((ext_vector_type(8)));
typedef float f32x4 __attribute__((ext_vector_type(4)));

__device__ inline bf16x8 load8(const float* p) {
  f32x4 a = *reinterpret_cast<const f32x4*>(p);
  f32x4 b = *reinterpret_cast<const f32x4*>(p + 4);
  bf16x8 r;
  r[0] = (bf16_t)a[0]; r[1] = (bf16_t)a[1];
  r[2] = (bf16_t)a[2]; r[3] = (bf16_t)a[3];
  r[4] = (bf16_t)b[0]; r[5] = (bf16_t)b[1];
  r[6] = (bf16_t)b[2]; r[7] = (bf16_t)b[3];
  return r;
}
__device__ inline bf16x8 load8(const bf16_t* p) {
  return *reinterpret_cast<const bf16x8*>(p);
}

// Async global->LDS 16B copy (gfx950). LDS dst is wave-uniform base +
// lane*16; global src is per-lane.
__device__ inline void gload_lds16(const bf16_t* g, bf16_t* l) {
  __builtin_amdgcn_global_load_lds(
      (const __attribute__((address_space(1))) void*)g,
      (__attribute__((address_space(3))) void*)l, 16, 0, 0);
}

// ---------------------------------------------------------------------------
// Fused convert: blocks 0..2047 copy x fp32->bf16; blocks 2048..2687 build
// the bf16-transposed weights (64x64 LDS tiles).
// ---------------------------------------------------------------------------
__global__ __launch_bounds__(256) void cvt_all_k(
    const float* __restrict__ x, bf16_t* __restrict__ xb,
    const float* __restrict__ Wq, const float* __restrict__ Wk,
    const float* __restrict__ Wv, const float* __restrict__ Wo,
    bf16_t* __restrict__ wqT, bf16_t* __restrict__ wkT,
    bf16_t* __restrict__ wvT, bf16_t* __restrict__ woT) {
  __shared__ bf16_t Ts[64][72];
  const int tid = threadIdx.x;
  if (blockIdx.x < 2048) {
    const size_t i = (size_t)blockIdx.x * 2048 + (size_t)tid * 8;
    *reinterpret_cast<bf16x8*>(xb + i) = load8(x + i);
    return;
  }
  const int b = blockIdx.x - 2048;
  const float* S;
  bf16_t* D;
  int N, idx;
  if (b < 256) { S = Wq; D = wqT; N = 1024; idx = b; }
  else if (b < 320) { S = Wk; D = wkT; N = 256; idx = b - 256; }
  else if (b < 384) { S = Wv; D = wvT; N = 256; idx = b - 320; }
  else { S = Wo; D = woT; N = 1024; idx = b - 384; }
  const int ntl = (N == 1024) ? 4 : 2;  // log2(n-tiles)
  const int kt0 = (idx >> ntl) * 64;
  const int n0 = (idx & ((1 << ntl) - 1)) * 64;
#pragma unroll
  for (int i = 0; i < 2; ++i) {
    const int c = tid + 256 * i;
    const int row = c >> 3, col0 = (c & 7) * 8;
    *reinterpret_cast<bf16x8*>(&Ts[row][col0]) =
        load8(&S[(size_t)(kt0 + row) * N + n0 + col0]);
  }
  __syncthreads();
#pragma unroll
  for (int i = 0; i < 2; ++i) {
    const int c = tid + 256 * i;
    const int nrow = c >> 3, k0 = (c & 7) * 8;
    bf16x8 v;
#pragma unroll
    for (int j = 0; j < 8; ++j) v[j] = Ts[k0 + j][nrow];
    *reinterpret_cast<bf16x8*>(&D[(size_t)(n0 + nrow) * 1024 + kt0 + k0]) = v;
  }
}

// ---------------------------------------------------------------------------
// 128x64 GEMM body, B^T form: C = A[M,K] * BT[N,K]^T, all bf16, BK=32.
// gload_lds staging, LDS double-buffered, one barrier per K-step.
// Linear LDS with k-block XOR swizzle cb ^= (row>>1)&3 applied inversely on
// the per-lane GLOBAL src (rule 21). qkv grid 768 = 3.0 blocks/CU,
// out-proj 512 = 2.0/CU.
// MFMA layouts (verified m89):
//   A: lane holds A[m=lane&15][k=(lane>>4)*8+j]
//   B: lane holds B[k=(lane>>4)*8+j][n=lane&15]  (= BT[n][k] rows)
//   C/D: row=(lane>>4)*4+reg, col=lane&15
// ---------------------------------------------------------------------------
__device__ inline void stage_gldsA(const bf16_t* __restrict__ G, int grow0,
                                   int gK, int k0, bf16_t* lds, int w, int l) {
#pragma unroll
  for (int i = 0; i < 2; ++i) {
    const int seg = w * 2 + i;                // 0..7
    const int r = (seg << 4) + (l >> 2);      // tile row 0..127
    const int cb = (l & 3) ^ ((r >> 1) & 3);  // swizzled global k-block
    gload_lds16(G + (size_t)(grow0 + r) * gK + k0 + cb * 8, lds + (seg << 9));
  }
}
__device__ inline void stage_gldsB(const bf16_t* __restrict__ G, int grow0,
                                   int gK, int k0, bf16_t* lds, int w, int l) {
  const int r = (w << 4) + (l >> 2);        // tile row 0..63
  const int cb = (l & 3) ^ ((r >> 1) & 3);  // swizzled global k-block
  gload_lds16(G + (size_t)(grow0 + r) * gK + k0 + cb * 8, lds + (w << 9));
}

template <typename OutT>
__device__ inline void gemm_bt_body(const bf16_t* __restrict__ A,
                                    const bf16_t* __restrict__ BT,
                                    OutT* __restrict__ C, int m0, int bt0,
                                    int K, int CN, int cn0, float alpha) {
  __shared__ __align__(16) bf16_t As[2][128][32];
  __shared__ __align__(16) bf16_t Bs[2][64][32];  // [n][k]

  const int tid = threadIdx.x;
  const int wave = tid >> 6, lane = tid & 63;
  const int quad = lane >> 4, l16 = lane & 15;
  const int moff = (wave & 1) * 64, noff = (wave >> 1) * 32;

  f32x4 acc[4][2];
#pragma unroll
  for (int mt = 0; mt < 4; ++mt)
#pragma unroll
    for (int nt = 0; nt < 2; ++nt) acc[mt][nt] = {0.f, 0.f, 0.f, 0.f};

  stage_gldsA(A, m0, K, 0, &As[0][0][0], wave, lane);
  stage_gldsB(BT, bt0, K, 0, &Bs[0][0][0], wave, lane);

  for (int k0 = 0; k0 < K; k0 += 32) {
    const int c = (k0 >> 5) & 1;
    __syncthreads();  // vmcnt(0) drain: buffer c ready; buffer c^1 free
    if (k0 + 32 < K) {
      stage_gldsA(A, m0, K, k0 + 32, &As[c ^ 1][0][0], wave, lane);
      stage_gldsB(BT, bt0, K, k0 + 32, &Bs[c ^ 1][0][0], wave, lane);
    }
    bf16x8 af[4], bfr[2];
#pragma unroll
    for (int mt = 0; mt < 4; ++mt) {
      const int row = moff + mt * 16 + l16;
      af[mt] = *reinterpret_cast<const bf16x8*>(
          &As[c][row][(quad ^ ((row >> 1) & 3)) * 8]);
    }
#pragma unroll
    for (int nt = 0; nt < 2; ++nt) {
      const int row = noff + nt * 16 + l16;
      bfr[nt] = *reinterpret_cast<const bf16x8*>(
          &Bs[c][row][(quad ^ ((row >> 1) & 3)) * 8]);
    }
#pragma unroll
    for (int mt = 0; mt < 4; ++mt)
#pragma unroll
      for (int nt = 0; nt < 2; ++nt)
        acc[mt][nt] = __builtin_amdgcn_mfma_f32_16x16x32_bf16(
            af[mt], bfr[nt], acc[mt][nt], 0, 0, 0);
  }

#pragma unroll
  for (int mt = 0; mt < 4; ++mt) {
    const int crow = m0 + moff + mt * 16 + quad * 4;
#pragma unroll
    for (int nt = 0; nt < 2; ++nt) {
      const int ccol = cn0 + noff + nt * 16 + l16;
#pragma unroll
      for (int r = 0; r < 4; ++r)
        C[(size_t)(crow + r) * CN + ccol] = (OutT)(acc[mt][nt][r] * alpha);
    }
  }
}

// Fused QKV projection: 64-wide n-tiles [Wq 0..15 | Wk 16..19 | Wv 20..23].
__global__ __launch_bounds__(256, 3) void qkv_k(
    const bf16_t* __restrict__ x, const bf16_t* __restrict__ wqT,
    const bf16_t* __restrict__ wkT, const bf16_t* __restrict__ wvT,
    bf16_t* __restrict__ Qo, bf16_t* __restrict__ Ko, bf16_t* __restrict__ Vo) {
  const int n0 = blockIdx.x * 64;
  const int m0 = blockIdx.y * 128;
  const bf16_t* BT;
  bf16_t* C;
  int CN, bn0;
  float alpha;
  if (n0 < 1024) {
    BT = wqT; C = Qo; CN = 1024; bn0 = n0; alpha = 0.125f;  // attn scale
  } else if (n0 < 1280) {
    BT = wkT; C = Ko; CN = 256; bn0 = n0 - 1024; alpha = 1.0f;
  } else {
    BT = wvT; C = Vo; CN = 256; bn0 = n0 - 1280; alpha = 1.0f;
  }
  gemm_bt_body<bf16_t>(x, BT, C, m0, bn0, 1024, CN, bn0, alpha);
}

// Plain B^T GEMM (attn @ Wo^T^T), 64-wide n-tiles.
template <typename OutT>
__global__ __launch_bounds__(256, 3) void gemm_bt_k(
    const bf16_t* __restrict__ A, const bf16_t* __restrict__ BT,
    OutT* __restrict__ C, int K, int N, float alpha) {
  gemm_bt_body<OutT>(A, BT, C, blockIdx.y * 128, blockIdx.x * 64, K, N,
                     blockIdx.x * 64, alpha);
}

// ---------------------------------------------------------------------------
// Transpose V [4096,256] -> VT[(g*4+kh)*64 + d][key].
// ---------------------------------------------------------------------------
__global__ __launch_bounds__(256) void transpose_v_k(
    const bf16_t* __restrict__ V, bf16_t* __restrict__ VT) {
  __shared__ bf16_t Vs[64][72];
  const int tid = threadIdx.x;
  const int kt0 = blockIdx.x * 64;
  const int ghk = blockIdx.y;  // g*4+kh
  const int g = ghk >> 2, kh = ghk & 3;
#pragma unroll
  for (int i = 0; i < 2; ++i) {
    const int c = tid + 256 * i;
    const int row = c >> 3, d0 = (c & 7) * 8;
    *reinterpret_cast<bf16x8*>(&Vs[row][d0]) = *reinterpret_cast<const bf16x8*>(
        &V[((size_t)(kt0 + row) * 2 + g) * 256 + kh * 64 + d0]);
  }
  __syncthreads();
#pragma unroll
  for (int i = 0; i < 2; ++i) {
    const int c = tid + 256 * i;
    const int d = c >> 3, k0 = (c & 7) * 8;
    bf16x8 v;
#pragma unroll
    for (int j = 0; j < 8; ++j) v[j] = Vs[k0 + j][d];
    *reinterpret_cast<bf16x8*>(&VT[((size_t)ghk * 64 + d) * 2048 + kt0 + k0]) =
        v;
  }
}

// ---------------------------------------------------------------------------
// Flash attention v13 = flash10 (r4-verified 4-wave x 16q, single-buffer
// 2-barrier relay, 4 waves/SIMD) + swapped-QK^T softmax (T12-lite):
// A and B fragments of mfma_16x16x32_bf16 share the same per-lane register
// layout (m89), so mfma(kf,qf) computes S^T for free. Each lane then holds
// 4 CONSECUTIVE keys (16nt+4quad+r) for one q=l16, so the Ps roundtrip
// becomes 4x ds_write_b64 + 2x ds_read_b128 (was 16x b16 + 2x b128) —
// ~70 LDS cyc/wave-iter saved of ~360 (r8 model, 4-wave regime confirmed
// LDS-bound). Ps rows padded to 72 elems (144B = 36 banks) for uniform
// bank spread, no XOR swizzle. kf/vf/qf loads, PV mfmas, O epilogue
// addressing unchanged from the verified kernel. lp is now a scalar per
// lane (q=l16), reduced over quads (shfl_xor 16,32) and redistributed
// with one shfl per output row.
// LDS 25 KB (Ks 8K + Vs 8K + Ps 9K) -> 4 blocks/CU (wave-capped).
// (r9: infra failure, resubmitted unchanged after full algebra re-audit.)
// ---------------------------------------------------------------------------
__global__ __launch_bounds__(256)
__attribute__((amdgpu_waves_per_eu(4, 4))) void flash13_k(
    const bf16_t* __restrict__ Q, const bf16_t* __restrict__ K,
    const bf16_t* __restrict__ VT, bf16_t* __restrict__ ATTN) {
  __shared__ __align__(16) bf16_t Ks[64][64];
  __shared__ __align__(16) bf16_t Vs[64][64];  // [d][key_local], swizzled
  __shared__ __align__(16) bf16_t Ps[4][16][72];  // [wave][q][key+pad]

  const int tid = threadIdx.x;
  const int w = tid >> 6, lane = tid & 63;
  const int quad = lane >> 4, l16 = lane & 15;
  const int b = blockIdx.x;  // 0..31
  const int gh = blockIdx.y;
  const int j8 = b & 7;
  const int i8e = ((b >> 3) + (gh >> 3)) & 3;  // gh-rotated length class
  const int T = (i8e == 0) ? j8
              : (i8e == 1) ? (15 - j8)
              : (i8e == 2) ? (16 + j8)
                           : (31 - j8);
  const int g = gh >> 4, h = gh & 15, kh = h >> 2;
  const int qrow0 = T * 64 + w * 16;  // wave's first query row
  const int rsw = l16 & 7;  // row-dependent K/V col-block swizzle key

  bf16x8 qf[2];
#pragma unroll
  for (int t = 0; t < 2; ++t)
    qf[t] = *reinterpret_cast<const bf16x8*>(
        &Q[((size_t)(qrow0 + l16) * 2 + g) * 1024 + h * 64 + t * 32 +
           quad * 8]);

  f32x4 O[4];
  float lp = 0.f;  // denominator for q = l16 (partial: this quad's keys)
#pragma unroll
  for (int d = 0; d < 4; ++d) O[d] = {0.f, 0.f, 0.f, 0.f};

  bf16x8 kr[2], vr[2];
#pragma unroll
  for (int i = 0; i < 2; ++i) {
    const int c = tid + 256 * i;
    const int row = c >> 3, e0 = (c & 7) * 8;
    kr[i] = *reinterpret_cast<const bf16x8*>(
        &K[((size_t)(row)*2 + g) * 256 + kh * 64 + e0]);
    vr[i] = *reinterpret_cast<const bf16x8*>(
        &VT[((size_t)(g * 4 + kh) * 64 + row) * 2048 + e0]);
  }

  for (int kt = 0; kt <= T; ++kt) {
#pragma unroll
    for (int i = 0; i < 2; ++i) {
      const int c = tid + 256 * i;
      const int row = c >> 3;
      const int pb = (((c & 7) ^ (row & 7)) << 3);  // swizzled col block
      *reinterpret_cast<bf16x8*>(&Ks[row][pb]) = kr[i];
      *reinterpret_cast<bf16x8*>(&Vs[row][pb]) = vr[i];
    }
    __syncthreads();
    if (kt < T) {
      const int nt0 = (kt + 1) * 64;
#pragma unroll
      for (int i = 0; i < 2; ++i) {
        const int c = tid + 256 * i;
        const int row = c >> 3, e0 = (c & 7) * 8;
        kr[i] = *reinterpret_cast<const bf16x8*>(
            &K[((size_t)(nt0 + row) * 2 + g) * 256 + kh * 64 + e0]);
        vr[i] = *reinterpret_cast<const bf16x8*>(
            &VT[((size_t)(g * 4 + kh) * 64 + row) * 2048 + nt0 + e0]);
      }
    }

    // QK^T swapped: S^T[key][q]; lane holds q=l16, key=16nt+4quad+r.
    f32x4 s[4];
    __builtin_amdgcn_s_setprio(1);
#pragma unroll
    for (int nt = 0; nt < 4; ++nt) {
      bf16x8 kf0 = *reinterpret_cast<const bf16x8*>(
          &Ks[nt * 16 + l16][(quad ^ rsw) << 3]);
      bf16x8 kf1 = *reinterpret_cast<const bf16x8*>(
          &Ks[nt * 16 + l16][((4 + quad) ^ rsw) << 3]);
      f32x4 z = {0.f, 0.f, 0.f, 0.f};
      z = __builtin_amdgcn_mfma_f32_16x16x32_bf16(kf0, qf[0], z, 0, 0, 0);
      s[nt] = __builtin_amdgcn_mfma_f32_16x16x32_bf16(kf1, qf[1], z, 0, 0, 0);
    }
    __builtin_amdgcn_s_setprio(0);
    const bool diag = (kt == T);
    const int qloc = w * 16 + l16;  // tile-local q row
#pragma unroll
    for (int nt = 0; nt < 4; ++nt) {
      bf16x4 pk;
#pragma unroll
      for (int r = 0; r < 4; ++r) {
        float p = __expf(s[nt][r]);
        if (diag && (nt * 16 + quad * 4 + r) > qloc) p = 0.f;
        lp += p;
        pk[r] = (bf16_t)p;
      }
      *reinterpret_cast<bf16x4*>(&Ps[w][l16][nt * 16 + quad * 4]) = pk;
    }
    bf16x8 pf[2];
#pragma unroll
    for (int t = 0; t < 2; ++t)
      pf[t] = *reinterpret_cast<const bf16x8*>(
          &Ps[w][l16][t * 32 + quad * 8]);
    __builtin_amdgcn_s_setprio(1);
#pragma unroll
    for (int dnt = 0; dnt < 4; ++dnt) {
      bf16x8 vf0 = *reinterpret_cast<const bf16x8*>(
          &Vs[dnt * 16 + l16][(quad ^ rsw) << 3]);
      bf16x8 vf1 = *reinterpret_cast<const bf16x8*>(
          &Vs[dnt * 16 + l16][((4 + quad) ^ rsw) << 3]);
      O[dnt] = __builtin_amdgcn_mfma_f32_16x16x32_bf16(pf[0], vf0, O[dnt], 0,
                                                       0, 0);
      O[dnt] = __builtin_amdgcn_mfma_f32_16x16x32_bf16(pf[1], vf1, O[dnt], 0,
                                                       0, 0);
    }
    __builtin_amdgcn_s_setprio(0);
    __syncthreads();
  }

  // Full denominator for q=l16: sum the 4 quad-lane partials.
  lp += __shfl_xor(lp, 16, 64);
  lp += __shfl_xor(lp, 32, 64);
  // O rows are q = quad*4+r (C/D layout); fetch matching denominator.
#pragma unroll
  for (int r = 0; r < 4; ++r) {
    const float inv = 1.f / __shfl(lp, quad * 4 + r, 64);
    const int row = qrow0 + quad * 4 + r;
#pragma unroll
    for (int dnt = 0; dnt < 4; ++dnt)
      ATTN[((size_t)row * 2 + g) * 1024 + h * 64 + dnt * 16 + l16] =
          (bf16_t)(O[dnt][r] * inv);
  }
}

// ---------------------------------------------------------------------------
extern "C" void kernel_launch(void* const* d_in, const int* in_sizes, int n_in,
                              void* d_out, int out_size, void* d_ws,
                              size_t ws_size, hipStream_t stream) {
  (void)in_sizes;
  (void)n_in;
  (void)out_size;
  (void)ws_size;

  const float* x = (const float*)d_in[0];   // [4096,1024] fp32
  const float* Wq = (const float*)d_in[1];  // [1024,1024]
  const float* Wk = (const float*)d_in[2];  // [1024,256]
  const float* Wv = (const float*)d_in[3];  // [1024,256]
  const float* Wo = (const float*)d_in[4];  // [1024,1024]
  float* out = (float*)d_out;               // [4096,1024] fp32 (16 MB)

  const size_t MB = 1024 * 1024;
  // d_out: [0,8M) Qtmp | [8M,10M) VT | [10M,13M) wqT/wkT/wvT | [13M,15M) Vo
  // (all dead before the final GEMM writes out; final GEMM reads only ws).
  char* ob = (char*)d_out;
  bf16_t* Qtmp = (bf16_t*)ob;
  bf16_t* VTws = (bf16_t*)(ob + 8 * MB);
  bf16_t* wqT = (bf16_t*)(ob + 10 * MB);
  bf16_t* wkT = (bf16_t*)(ob + 12 * MB);
  bf16_t* wvT = (bf16_t*)(ob + 12 * MB + 512 * 1024);
  bf16_t* Vws = (bf16_t*)(ob + 13 * MB);
  // ws (12 MB): [0,2M) K | [2M,4M) woT | [4M,12M) ATTN (xb borrows upfront).
  char* wb = (char*)d_ws;
  bf16_t* Kws = (bf16_t*)wb;
  bf16_t* woT = (bf16_t*)(wb + 2 * MB);
  bf16_t* ATTNws = (bf16_t*)(wb + 4 * MB);
  bf16_t* xb = ATTNws;  // 8 MB, dead once flash starts writing ATTN

  cvt_all_k<<<dim3(2688), dim3(256), 0, stream>>>(x, xb, Wq, Wk, Wv, Wo, wqT,
                                                  wkT, wvT, woT);
  qkv_k<<<dim3(24, 32), dim3(256), 0, stream>>>(xb, wqT, wkT, wvT, Qtmp, Kws,
                                                Vws);
  transpose_v_k<<<dim3(32, 8), dim3(256), 0, stream>>>(Vws, VTws);
  flash13_k<<<dim3(32, 32), dim3(256), 0, stream>>>(Qtmp, Kws, VTws, ATTNws);
  gemm_bt_k<float><<<dim3(16, 32), dim3(256), 0, stream>>>(ATTNws, woT, out,
                                                           1024, 1024, 1.0f);
}